// Round 4
// baseline (885.423 us; speedup 1.0000x reference)
//
#include <hip/hip_runtime.h>

// CenterLoss: features [B,D] f32, centers [C,D] f32, labels [B] int32
// out = [loss (1 f32)] ++ [new_centers (C*D f32)]
// new_centers[c] = count[c]>0 ? (1-ALPHA)*centers[c] + ALPHA*mean_c : centers[c]
// NOTE: relies on ALPHA == 0.5 so (1-ALPHA) == ALPHA.

constexpr int B = 16384;
constexpr int D = 128;
constexpr int C = 1000000;
constexpr int QPR = D / 4;      // float4 quads per row = 32
constexpr float ALPHA = 0.5f;   // momentum; LAMBDA_C = 1.0 folded in

// Clang-native vector type: __builtin_nontemporal_* requires a real vector,
// not HIP_vector_type<float,4>.
typedef float f32x4 __attribute__((ext_vector_type(4)));

// Workspace layout (ints): [0,C) counts | [C] nuniq | [C+1, C+1+B) uniq list

// Count labels AND build a compacted list of unique (present) labels.
// The thread whose atomicAdd returns 0 owns the label and registers it.
__global__ void count_uniq_k(const int* __restrict__ labels,
                             int* __restrict__ counts,
                             int* __restrict__ nuniq,
                             int* __restrict__ uniq) {
    int b = blockIdx.x * 256 + threadIdx.x;
    if (b < B) {
        int lbl = labels[b];
        if (atomicAdd(counts + lbl, 1) == 0) {
            int pos = atomicAdd(nuniq, 1);
            uniq[pos] = lbl;
        }
    }
}

__global__ void loss_k(const float4* __restrict__ f4,
                       const float4* __restrict__ c4,
                       const int* __restrict__ labels,
                       float* __restrict__ out) {
    int tid = blockIdx.x * blockDim.x + threadIdx.x;
    int nth = gridDim.x * blockDim.x;
    float acc = 0.f;
    for (int idx = tid; idx < B * QPR; idx += nth) {
        int b = idx >> 5;          // idx / QPR
        int q = idx & (QPR - 1);
        float4 f = f4[idx];
        float4 c = c4[(long long)labels[b] * QPR + q];
        float dx = f.x - c.x, dy = f.y - c.y, dz = f.z - c.z, dw = f.w - c.w;
        acc += dx * dx + dy * dy + dz * dz + dw * dw;
    }
    for (int off = 32; off > 0; off >>= 1)
        acc += __shfl_down(acc, off, 64);
    __shared__ float ws[4];
    int lane = threadIdx.x & 63, wid = threadIdx.x >> 6;
    if (lane == 0) ws[wid] = acc;
    __syncthreads();
    if (threadIdx.x == 0) {
        float s = ws[0] + ws[1] + ws[2] + ws[3];
        atomicAdd(out, s * (1.0f / (2.0f * (float)B)));
    }
}

// Bulk copy centers -> out+1 with BOTH sides 16B-aligned.
// dst quad m (at out + 4m, 16B-aligned) = {src[4m-1], src[4m], src[4m+1], src[4m+2]}.
// src[4m-1] comes from the neighbor lane's aligned load via shfl_up; the first
// lane of each wave fills in with one scalar load. Thread m==0 instead writes
// out[1..3] and patches the tail element out[C*D] = src[C*D-1].
__global__ void __launch_bounds__(256) copy_k(const f32x4* __restrict__ src4,
                                              float* __restrict__ out) {
    const float* src = (const float*)src4;
    const int total = C * QPR;               // 32,000,000 quads
    const int lane = threadIdx.x & 63;
    const int nth = gridDim.x * blockDim.x;
    int m0 = blockIdx.x * blockDim.x + threadIdx.x;
    if (m0 == 0) {
        // Loop-invariant patches: first 3 elements + tail element.
        out[1] = src[0]; out[2] = src[1]; out[3] = src[2];
        out[(long long)C * D] = src[(long long)C * D - 1];
    }
    for (int m = m0; m < total; m += nth) {
        f32x4 v = __builtin_nontemporal_load(src4 + m);    // src[4m..4m+3]
        float wprev = __shfl_up(v.w, 1, 64);
        if (lane == 0 && m > 0) wprev = src[4 * m - 1];
        if (m > 0) {
            f32x4 o;
            o.x = wprev; o.y = v.x; o.z = v.y; o.w = v.z;
            __builtin_nontemporal_store(o, (f32x4*)out + m);   // 16B-aligned
        }
    }
}

// Scale ONLY present rows by ALPHA (<= 16384 rows, ~16 MB traffic).
// One wave per unique label.
__global__ void scale_k(const int* __restrict__ nuniq,
                        const int* __restrict__ uniq,
                        float* __restrict__ outc) {
    int w = (blockIdx.x * blockDim.x + threadIdx.x) >> 6;  // global wave id
    int lane = threadIdx.x & 63;
    if (w >= *nuniq) return;                               // wave-uniform predicate
    int row = uniq[w];
    float* p = outc + (long long)row * D;
    p[lane]      *= ALPHA;
    p[lane + 64] *= ALPHA;
}

// Accumulate ALPHA * features[b] / count into present rows.
__global__ void scatter_k(const float4* __restrict__ f4,
                          const int* __restrict__ labels,
                          const int* __restrict__ counts,
                          float* __restrict__ outc) {
    int idx = blockIdx.x * 256 + threadIdx.x;
    if (idx >= B * QPR) return;
    int b = idx >> 5, q = idx & (QPR - 1);
    int lbl = labels[b];
    float inv = ALPHA / (float)counts[lbl];
    float4 f = f4[idx];
    float* p = outc + (long long)lbl * D + q * 4;
    atomicAdd(p + 0, f.x * inv);
    atomicAdd(p + 1, f.y * inv);
    atomicAdd(p + 2, f.z * inv);
    atomicAdd(p + 3, f.w * inv);
}

extern "C" void kernel_launch(void* const* d_in, const int* in_sizes, int n_in,
                              void* d_out, int out_size, void* d_ws, size_t ws_size,
                              hipStream_t stream) {
    const float* features = (const float*)d_in[0];
    const float* centers  = (const float*)d_in[1];
    const int*   labels   = (const int*)d_in[2];
    float* out = (float*)d_out;

    int* counts = (int*)d_ws;        // C ints
    int* nuniq  = counts + C;        // 1 int
    int* uniq   = nuniq + 1;         // B ints

    hipMemsetAsync(counts, 0, (size_t)(C + 1) * sizeof(int), stream);
    hipMemsetAsync(d_out, 0, sizeof(float), stream);

    count_uniq_k<<<(B + 255) / 256, 256, 0, stream>>>(labels, counts, nuniq, uniq);
    loss_k<<<1024, 256, 0, stream>>>((const float4*)features, (const float4*)centers,
                                     labels, out);
    // 2048 blocks x 256 = 8 blocks/CU -> full occupancy, grid-stride copy.
    copy_k<<<2048, 256, 0, stream>>>((const f32x4*)centers, out);
    scale_k<<<(B * 64) / 256, 256, 0, stream>>>(nuniq, uniq, out + 1);
    scatter_k<<<(B * QPR + 255) / 256, 256, 0, stream>>>((const float4*)features, labels,
                                                         counts, out + 1);
}